// Round 1
// baseline (251.436 us; speedup 1.0000x reference)
//
#include <hip/hip_runtime.h>
#include <cstdint>
#include <cstddef>

// ---------------------------------------------------------------------------
// SelfAttention block on MI355X (gfx950), bf16 MFMA path.
//   x:[2,2048,1024] f32.  QKV proj -> 16-head attn (S=2048, HD=64) -> out proj
//   -> +x -> LayerNorm.  Output f32 [2,2048,1024].
// ---------------------------------------------------------------------------

typedef short  b16x8 __attribute__((ext_vector_type(8)));   // 8 bf16 (4 VGPRs)
typedef float  f32x4 __attribute__((ext_vector_type(4)));   // MFMA acc

#define AS1 __attribute__((address_space(1)))
#define AS3 __attribute__((address_space(3)))

__device__ __forceinline__ unsigned short f2bf(float f) {   // RNE f32->bf16
    unsigned int u = __builtin_bit_cast(unsigned int, f);
    u += 0x7FFFu + ((u >> 16) & 1u);
    return (unsigned short)(u >> 16);
}

// ---------------- convert x (f32) -> bf16 ----------------
__global__ __launch_bounds__(256) void k_cvt_x(const float* __restrict__ x,
                                               unsigned short* __restrict__ xb) {
    int i = blockIdx.x * 256 + threadIdx.x;          // 1M threads * 4 elems
    float4 v = ((const float4*)x)[i];
    ushort4 o;
    o.x = f2bf(v.x); o.y = f2bf(v.y); o.z = f2bf(v.z); o.w = f2bf(v.w);
    ((ushort4*)xb)[i] = o;
}

// ---------------- transpose+convert W[k][n] f32 -> Wt[n][k] bf16 ----------------
__global__ __launch_bounds__(1024) void k_cvt_w(
    const float* __restrict__ W0, const float* __restrict__ W1,
    const float* __restrict__ W2, const float* __restrict__ W3,
    unsigned short* __restrict__ T0, unsigned short* __restrict__ T1,
    unsigned short* __restrict__ T2, unsigned short* __restrict__ T3) {
    const float* W = blockIdx.z == 0 ? W0 : blockIdx.z == 1 ? W1 : blockIdx.z == 2 ? W2 : W3;
    unsigned short* T = blockIdx.z == 0 ? T0 : blockIdx.z == 1 ? T1 : blockIdx.z == 2 ? T2 : T3;
    __shared__ float tile[32][33];
    int k0 = blockIdx.x * 32, n0 = blockIdx.y * 32;
    int tx = threadIdx.x, ty = threadIdx.y;
    tile[ty][tx] = W[(size_t)(k0 + ty) * 1024 + n0 + tx];
    __syncthreads();
    T[(size_t)(n0 + ty) * 1024 + k0 + tx] = f2bf(tile[tx][ty]);
}

// ---------------- m97-style 128x128 bf16 GEMM ----------------
// C[M=4096,N=1024] = A[4096,1024] @ Bt^T + bias.  Bt is [n][k].
// mode 0: Q (scatter [B,H,S,HD] bf16, *0.125)  1/2: K/V (scatter bf16)
// mode 3: proj (f32 [row][col])
__global__ __launch_bounds__(256) void k_gemm(
    const unsigned short* __restrict__ A, const unsigned short* __restrict__ Bt,
    const float* __restrict__ bias, void* __restrict__ out, int mode) {
    __shared__ unsigned short As[128 * 32];
    __shared__ unsigned short Bs[128 * 32];
    const int tid = threadIdx.x, lane = tid & 63, wid = tid >> 6;
    const int m0 = blockIdx.y * 128, n0 = blockIdx.x * 128;
    const int wr = wid >> 1, wc = wid & 1;
    f32x4 acc[4][4] = {};

    // staging: wave w covers rows [32w,32w+32): 2 chunks of 16 rows, 1KB each
    const int srow = wid * 32 + (lane >> 2);
    const int scol = (lane & 3) * 8;                     // ushort offset in 32-wide k row
    const unsigned short* Ag = A  + (size_t)(m0 + srow) * 1024 + scol;
    const unsigned short* Bg = Bt + (size_t)(n0 + srow) * 1024 + scol;
    char* AsB = (char*)As + wid * 2048;
    char* BsB = (char*)Bs + wid * 2048;

    for (int kt = 0; kt < 32; ++kt) {
        const unsigned short* a0 = Ag + kt * 32;
        const unsigned short* b0 = Bg + kt * 32;
        __builtin_amdgcn_global_load_lds((const AS1 void*)(a0),             (AS3 void*)(AsB),        16, 0, 0);
        __builtin_amdgcn_global_load_lds((const AS1 void*)(a0 + 16 * 1024), (AS3 void*)(AsB + 1024), 16, 0, 0);
        __builtin_amdgcn_global_load_lds((const AS1 void*)(b0),             (AS3 void*)(BsB),        16, 0, 0);
        __builtin_amdgcn_global_load_lds((const AS1 void*)(b0 + 16 * 1024), (AS3 void*)(BsB + 1024), 16, 0, 0);
        __syncthreads();   // drains vmcnt before ds_read
        const int g = lane >> 4, r = lane & 15;
        b16x8 af[4], bfr[4];
        for (int mi = 0; mi < 4; ++mi)
            af[mi] = __builtin_bit_cast(b16x8, *(const uint4*)(As + (wr * 64 + mi * 16 + r) * 32 + g * 8));
        for (int ni = 0; ni < 4; ++ni)
            bfr[ni] = __builtin_bit_cast(b16x8, *(const uint4*)(Bs + (wc * 64 + ni * 16 + r) * 32 + g * 8));
        for (int mi = 0; mi < 4; ++mi)
            for (int ni = 0; ni < 4; ++ni)
                acc[mi][ni] = __builtin_amdgcn_mfma_f32_16x16x32_bf16(af[mi], bfr[ni], acc[mi][ni], 0, 0, 0);
        __syncthreads();
    }

    const int g = lane >> 4, r = lane & 15;
    for (int mi = 0; mi < 4; ++mi)
        for (int ni = 0; ni < 4; ++ni) {
            int col = n0 + wc * 64 + ni * 16 + r;
            float bv = bias[col];
            for (int j = 0; j < 4; ++j) {
                int row = m0 + wr * 64 + mi * 16 + g * 4 + j;
                float v = acc[mi][ni][j] + bv;
                if (mode == 3) {
                    ((float*)out)[(size_t)row * 1024 + col] = v;
                } else {
                    if (mode == 0) v *= 0.125f;       // fold 1/sqrt(HD) into Q
                    int b = row >> 11, s = row & 2047, h = col >> 6, hd = col & 63;
                    ((unsigned short*)out)[((size_t)(b * 16 + h) * 2048 + s) * 64 + hd] = f2bf(v);
                }
            }
        }
}

// ---------------- V [B,H,S,HD] -> Vt [B,H,HD,S] ----------------
__global__ __launch_bounds__(256) void k_transpose_v(const unsigned short* __restrict__ Vb,
                                                     unsigned short* __restrict__ Vt) {
    __shared__ unsigned short T[64][80];          // 80 stride: 160B rows, 16B-aligned
    int bh = blockIdx.y, s0 = blockIdx.x * 64;
    int t = threadIdx.x;
    int r = t >> 2, cq = t & 3;
    const unsigned short* src = Vb + ((size_t)bh * 2048 + s0 + r) * 64 + cq * 16;
    *(uint4*)&T[r][cq * 16]     = *(const uint4*)src;
    *(uint4*)&T[r][cq * 16 + 8] = *(const uint4*)(src + 8);
    __syncthreads();
    __align__(16) unsigned short tmp[16];
    for (int i = 0; i < 16; ++i) tmp[i] = T[cq * 16 + i][r];
    unsigned short* dst = Vt + ((size_t)bh * 64 + r) * 2048 + s0 + cq * 16;
    *(uint4*)dst       = *(uint4*)tmp;
    *(uint4*)(dst + 8) = *(uint4*)(tmp + 8);
}

// ---------------- flash attention ----------------
// Qb/Kb: [BH, S, 64] bf16 (Q pre-scaled).  Vt: [BH, 64, S] bf16.
// ctx out: [B, S, 1024] bf16.  grid (S/64, BH), 256 thr (4 waves).
#define SW(rr, cb) ((((rr) * 128) + (cb)) ^ (((rr) & 7) << 4))   // bank swizzle

__global__ __launch_bounds__(256) void k_attn(const unsigned short* __restrict__ Qb,
                                              const unsigned short* __restrict__ Kb,
                                              const unsigned short* __restrict__ Vt,
                                              unsigned short* __restrict__ ctx) {
    __shared__ unsigned short Qs[64 * 64];
    __shared__ unsigned short Ks[64 * 64];
    __shared__ unsigned short Vs[64 * 64];      // rows = hd, cols = kv
    __shared__ unsigned short Ps[64 * 64];
    __shared__ float Ss[64 * 68];
    __shared__ float m_run[64], l_run[64], alpha_s[64];

    const int tid = threadIdx.x, lane = tid & 63, w = tid >> 6;
    const int q0 = blockIdx.x * 64, bh = blockIdx.y;
    const int b = bh >> 4, h = bh & 15;

    {   // stage Q tile (swizzled), init running stats
        int r = tid >> 2, cb = (tid & 3) * 32;
        const char* src = (const char*)(Qb + ((size_t)bh * 2048 + q0 + r) * 64) + cb;
        uint4 v0 = *(const uint4*)src, v1 = *(const uint4*)(src + 16);
        *(uint4*)((char*)Qs + SW(r, cb))      = v0;
        *(uint4*)((char*)Qs + SW(r, cb + 16)) = v1;
        if (tid < 64) { m_run[tid] = -1e30f; l_run[tid] = 0.f; }
    }
    f32x4 oacc[4] = {};

    for (int kt = 0; kt < 32; ++kt) {
        __syncthreads();                       // prev iter done with Ks/Vs
        {   // stage K tile and V^T tile
            int r = tid >> 2, cb = (tid & 3) * 32;
            const char* ks = (const char*)(Kb + ((size_t)bh * 2048 + kt * 64 + r) * 64) + cb;
            uint4 k0v = *(const uint4*)ks, k1v = *(const uint4*)(ks + 16);
            const char* vs = (const char*)(Vt + ((size_t)bh * 64 + r) * 2048 + kt * 64) + cb;
            uint4 v0v = *(const uint4*)vs, v1v = *(const uint4*)(vs + 16);
            *(uint4*)((char*)Ks + SW(r, cb))      = k0v;
            *(uint4*)((char*)Ks + SW(r, cb + 16)) = k1v;
            *(uint4*)((char*)Vs + SW(r, cb))      = v0v;
            *(uint4*)((char*)Vs + SW(r, cb + 16)) = v1v;
        }
        __syncthreads();
        {   // QK^T : wave w owns q-rows [16w,16w+16)
            f32x4 sacc[4] = {};
            const int rr = lane & 15, g = lane >> 4;
            for (int kk = 0; kk < 2; ++kk) {
                int ar = w * 16 + rr;
                b16x8 a = __builtin_bit_cast(b16x8, *(const uint4*)((char*)Qs + SW(ar, kk * 64 + g * 16)));
                for (int nt = 0; nt < 4; ++nt) {
                    int br = nt * 16 + rr;
                    b16x8 bb = __builtin_bit_cast(b16x8, *(const uint4*)((char*)Ks + SW(br, kk * 64 + g * 16)));
                    sacc[nt] = __builtin_amdgcn_mfma_f32_16x16x32_bf16(a, bb, sacc[nt], 0, 0, 0);
                }
            }
            for (int nt = 0; nt < 4; ++nt)
                for (int j = 0; j < 4; ++j)
                    Ss[(w * 16 + g * 4 + j) * 68 + nt * 16 + rr] = sacc[nt][j];
        }
        __syncthreads();
        {   // online softmax: 4 threads per row
            int r = tid >> 2, q4 = tid & 3;
            float vals[16];
            float mx = -1e30f;
            for (int i = 0; i < 16; ++i) { vals[i] = Ss[r * 68 + q4 * 16 + i]; mx = fmaxf(mx, vals[i]); }
            mx = fmaxf(mx, __shfl_xor(mx, 1, 64));
            mx = fmaxf(mx, __shfl_xor(mx, 2, 64));
            float mold = m_run[r];
            float Mn = fmaxf(mold, mx);
            float al = __expf(mold - Mn);
            float sum = 0.f;
            __align__(16) unsigned short pv[16];
            for (int i = 0; i < 16; ++i) { float p = __expf(vals[i] - Mn); sum += p; pv[i] = f2bf(p); }
            sum += __shfl_xor(sum, 1, 64);
            sum += __shfl_xor(sum, 2, 64);
            if (q4 == 0) { m_run[r] = Mn; l_run[r] = l_run[r] * al + sum; alpha_s[r] = al; }
            int cb = q4 * 32;
            *(uint4*)((char*)Ps + SW(r, cb))      = *(uint4*)pv;
            *(uint4*)((char*)Ps + SW(r, cb + 16)) = *(uint4*)(pv + 8);
        }
        __syncthreads();
        {   // rescale O, then O += P @ V
            const int rr = lane & 15, g = lane >> 4;
            float al[4];
            for (int j = 0; j < 4; ++j) al[j] = alpha_s[w * 16 + g * 4 + j];
            for (int nt = 0; nt < 4; ++nt)
                for (int j = 0; j < 4; ++j) oacc[nt][j] *= al[j];
            for (int kk = 0; kk < 2; ++kk) {
                int ar = w * 16 + rr;
                b16x8 a = __builtin_bit_cast(b16x8, *(const uint4*)((char*)Ps + SW(ar, kk * 64 + g * 16)));
                for (int nt = 0; nt < 4; ++nt) {
                    int br = nt * 16 + rr;   // hd row of V^T tile
                    b16x8 bb = __builtin_bit_cast(b16x8, *(const uint4*)((char*)Vs + SW(br, kk * 64 + g * 16)));
                    oacc[nt] = __builtin_amdgcn_mfma_f32_16x16x32_bf16(a, bb, oacc[nt], 0, 0, 0);
                }
            }
        }
    }
    {   // normalize + write ctx [B,S,H*HD]
        const int rr = lane & 15, g = lane >> 4;
        for (int j = 0; j < 4; ++j) {
            int r = w * 16 + g * 4 + j;
            float inv = 1.f / l_run[r];
            unsigned short* dst = ctx + ((size_t)(b * 2048 + q0 + r)) * 1024 + h * 64;
            for (int nt = 0; nt < 4; ++nt)
                dst[nt * 16 + rr] = f2bf(oacc[nt][j] * inv);
        }
    }
}

// ---------------- residual + LayerNorm ----------------
__global__ __launch_bounds__(256) void k_ln(const float* __restrict__ proj,
                                            const float* __restrict__ x,
                                            const float* __restrict__ gamma,
                                            const float* __restrict__ beta,
                                            float* __restrict__ out) {
    int row = blockIdx.x, t = threadIdx.x;
    int lane = t & 63, w = t >> 6;
    size_t base = (size_t)row * 256;
    float4 p  = ((const float4*)proj)[base + t];
    float4 xv = ((const float4*)x)[base + t];
    float4 y;
    y.x = p.x + xv.x; y.y = p.y + xv.y; y.z = p.z + xv.z; y.w = p.w + xv.w;
    float s  = y.x + y.y + y.z + y.w;
    float ss = y.x * y.x + y.y * y.y + y.z * y.z + y.w * y.w;
    for (int o = 32; o > 0; o >>= 1) { s += __shfl_down(s, o, 64); ss += __shfl_down(ss, o, 64); }
    __shared__ float red[8];
    if (lane == 0) { red[w] = s; red[4 + w] = ss; }
    __syncthreads();
    if (t == 0) {
        red[0] = red[0] + red[1] + red[2] + red[3];
        red[4] = red[4] + red[5] + red[6] + red[7];
    }
    __syncthreads();
    float mu  = red[0] * (1.f / 1024.f);
    float var = red[4] * (1.f / 1024.f) - mu * mu;
    float inv = rsqrtf(var + 1e-5f);
    float4 g  = ((const float4*)gamma)[t];
    float4 be = ((const float4*)beta)[t];
    float4 o4;
    o4.x = (y.x - mu) * inv * g.x + be.x;
    o4.y = (y.y - mu) * inv * g.y + be.y;
    o4.z = (y.z - mu) * inv * g.z + be.z;
    o4.w = (y.w - mu) * inv * g.w + be.w;
    ((float4*)out)[base + t] = o4;
}

// ---------------------------------------------------------------------------
extern "C" void kernel_launch(void* const* d_in, const int* in_sizes, int n_in,
                              void* d_out, int out_size, void* d_ws, size_t ws_size,
                              hipStream_t stream) {
    const float* x  = (const float*)d_in[0];
    const float* Wq = (const float*)d_in[1];
    const float* bq = (const float*)d_in[2];
    const float* Wk = (const float*)d_in[3];
    const float* bk = (const float*)d_in[4];
    const float* Wv = (const float*)d_in[5];
    const float* bv = (const float*)d_in[6];
    const float* Wo = (const float*)d_in[7];
    const float* bo = (const float*)d_in[8];
    const float* gamma = (const float*)d_in[9];
    const float* beta  = (const float*)d_in[10];

    char* ws = (char*)d_ws;
    const size_t MB = 1u << 20;
    unsigned short* xbf = (unsigned short*)(ws);             // 8 MiB; reused as ctx
    unsigned short* Wqt = (unsigned short*)(ws + 8 * MB);
    unsigned short* Wkt = (unsigned short*)(ws + 10 * MB);
    unsigned short* Wvt = (unsigned short*)(ws + 12 * MB);
    unsigned short* Wot = (unsigned short*)(ws + 14 * MB);
    unsigned short* Qb  = (unsigned short*)(ws + 16 * MB);   // 8 MiB
    unsigned short* Kb  = (unsigned short*)(ws + 24 * MB);   // 8 MiB
    unsigned short* Vb  = (unsigned short*)(ws + 32 * MB);   // 8 MiB
    unsigned short* Vtg = (unsigned short*)(ws + 40 * MB);   // 8 MiB
    float* proj = (float*)(ws + 16 * MB);                    // 16 MiB, overlays Qb+Kb (dead by then)
    unsigned short* ctx = xbf;                               // overlays xbf (dead after QKV GEMMs)

    k_cvt_x<<<4096, 256, 0, stream>>>(x, xbf);
    k_cvt_w<<<dim3(32, 32, 4), dim3(32, 32), 0, stream>>>(Wq, Wk, Wv, Wo, Wqt, Wkt, Wvt, Wot);
    k_gemm<<<dim3(8, 32), 256, 0, stream>>>(xbf, Wqt, bq, Qb, 0);
    k_gemm<<<dim3(8, 32), 256, 0, stream>>>(xbf, Wkt, bk, Kb, 1);
    k_gemm<<<dim3(8, 32), 256, 0, stream>>>(xbf, Wvt, bv, Vb, 2);
    k_transpose_v<<<dim3(32, 32), 256, 0, stream>>>(Vb, Vtg);
    k_attn<<<dim3(32, 32), 256, 0, stream>>>(Qb, Kb, Vtg, ctx);
    k_gemm<<<dim3(8, 32), 256, 0, stream>>>(ctx, Wot, bo, proj, 3);
    k_ln<<<4096, 256, 0, stream>>>(proj, x, gamma, beta, (float*)d_out);
}